// Round 1
// 14250.841 us; speedup vs baseline: 1.2784x; 1.2784x over previous
//
#include <hip/hip_runtime.h>
#include <hip/hip_bf16.h>

typedef unsigned short ushort_t;
typedef __attribute__((ext_vector_type(8))) short bf16x8;
typedef __attribute__((ext_vector_type(4))) float f32x4;
typedef __attribute__((ext_vector_type(2))) float f32x2;

#define B_SZ 32
#define T_SZ 2048
#define I_SZ 512
#define H_SZ 512
#define G_SZ 2048  // 4*H
#define T_C  64    // chunk length
#define N_CHUNK (T_SZ / T_C)

__device__ __forceinline__ ushort_t f2bf(float f) {
    union { float f; unsigned u32; } c; c.f = f;
    unsigned r = c.u32 + 0x7fffu + ((c.u32 >> 16) & 1u);
    return (ushort_t)(r >> 16);
}
__device__ __forceinline__ bf16x8 cvt8(const float* __restrict__ p) {
    f32x4 a = *(const f32x4*)p;
    f32x4 b = *(const f32x4*)(p + 4);
    bf16x8 v;
    v[0] = (short)f2bf(a[0]); v[1] = (short)f2bf(a[1]);
    v[2] = (short)f2bf(a[2]); v[3] = (short)f2bf(a[3]);
    v[4] = (short)f2bf(b[0]); v[5] = (short)f2bf(b[1]);
    v[6] = (short)f2bf(b[2]); v[7] = (short)f2bf(b[3]);
    return v;
}
__device__ __forceinline__ float sigf(float x) { return 1.0f / (1.0f + __expf(-x)); }
__device__ __forceinline__ float tanh_fast(float x) {
    float a = fabsf(x);
    float e = __expf(-2.0f * a);
    float t = (1.0f - e) / (1.0f + e);
    return x < 0.0f ? -t : t;
}

// ---------------------------------------------------------------------------
// Phase 1 (per chunk): gx[tc][b][g] = sum_k x[b][t0+tc][k]*Wi[g][k] + bi + bh
// fp32 in, bf16 staged in LDS, MFMA 16x16x32, fp32 out.  (unchanged)
// ---------------------------------------------------------------------------
__global__ __launch_bounds__(256) void gemm_gx(
    const float* __restrict__ X,   // [32][2048][512] fp32
    const float* __restrict__ Wi,  // [2048][512] fp32
    const float* __restrict__ bi,  // [2048] fp32
    const float* __restrict__ bh,  // [2048] fp32
    float* __restrict__ gx,        // [T_C][32][2048] fp32
    int t0)
{
    __shared__ ushort_t As[128][40];
    __shared__ ushort_t Bs[128][40];

    const int tid  = threadIdx.x;
    const int lane = tid & 63;
    const int wv   = tid >> 6;
    const int wm   = (wv >> 1) * 64;
    const int wn   = (wv & 1) * 64;
    const int m0   = blockIdx.y * 128;
    const int n0   = blockIdx.x * 128;

    f32x4 acc[4][4];
#pragma unroll
    for (int i = 0; i < 4; i++)
#pragma unroll
        for (int j = 0; j < 4; j++) acc[i][j] = (f32x4)0.0f;

    const int lrow   = tid >> 2;
    const int lchunk = (tid & 3) * 8;

    const int m1 = m0 + lrow, m2 = m1 + 64;
    const size_t xr1 = ((size_t)(m1 >> 6) * T_SZ + t0 + (m1 & (T_C - 1))) * 512;
    const size_t xr2 = ((size_t)(m2 >> 6) * T_SZ + t0 + (m2 & (T_C - 1))) * 512;

    for (int kk = 0; kk < 512; kk += 32) {
        *(bf16x8*)&As[lrow][lchunk]      = cvt8(X + xr1 + kk + lchunk);
        *(bf16x8*)&As[lrow + 64][lchunk] = cvt8(X + xr2 + kk + lchunk);
        const float* bp = Wi + (size_t)(n0 + lrow) * 512 + kk + lchunk;
        *(bf16x8*)&Bs[lrow][lchunk]      = cvt8(bp);
        *(bf16x8*)&Bs[lrow + 64][lchunk] = cvt8(bp + (size_t)64 * 512);
        __syncthreads();

        const int koff = (lane >> 4) * 8;
        const int rsel = lane & 15;
        bf16x8 af[4], bfr[4];
#pragma unroll
        for (int mt = 0; mt < 4; mt++) af[mt]  = *(const bf16x8*)&As[wm + mt * 16 + rsel][koff];
#pragma unroll
        for (int nt = 0; nt < 4; nt++) bfr[nt] = *(const bf16x8*)&Bs[wn + nt * 16 + rsel][koff];
#pragma unroll
        for (int mt = 0; mt < 4; mt++)
#pragma unroll
            for (int nt = 0; nt < 4; nt++)
                acc[mt][nt] = __builtin_amdgcn_mfma_f32_16x16x32_bf16(af[mt], bfr[nt], acc[mt][nt], 0, 0, 0);
        __syncthreads();
    }

    const int rsel = lane & 15;
    const int rq   = (lane >> 4) * 4;
#pragma unroll
    for (int nt = 0; nt < 4; nt++) {
        const int n = n0 + wn + nt * 16 + rsel;
        const float bias = bi[n] + bh[n];
#pragma unroll
        for (int mt = 0; mt < 4; mt++) {
#pragma unroll
            for (int r = 0; r < 4; r++) {
                const int m  = m0 + wm + mt * 16 + rq + r;
                const int b  = m >> 6;
                const int tc = m & (T_C - 1);
                gx[((size_t)tc * B_SZ + b) * G_SZ + n] = acc[mt][nt][r] + bias;
            }
        }
    }
}

// ---------------------------------------------------------------------------
// Phase 2 (per chunk): persistent scan, 32 WGs x 256 threads. WG w owns hidden
// [16w,16w+16); wave g owns gate g. Wh held as bf16 VGPR fragments.
//
// Sync redesign vs previous version: the central counter+generation barrier
// (32 serialized cross-XCD RMWs + broadcast hop + redundant acquire load) is
// replaced by 32 DISTRIBUTED epoch flags, one 128B line per WG:
//   writer:  h stores (relaxed, agent) -> __syncthreads (drains vmcnt)
//            -> tid0 release-stores flag[w] = t+1 (agent)
//   reader:  per-WAVE poll of all 32 flags (lane -> flag[lane&31]) with
//            relaxed loads until __all(flag >= t), then ONE
//            fence(acquire, agent) (invalidates L1/L2 -> fresh h loads).
// Max skew between WGs remains 1 step -> parity double-buffer of h still
// bounds it (flag[*] >= t+1 implies every WG finished READING h(t), so
// buffer (t&1) is safe to overwrite at step t+1).
// gx for step t is prefetched into registers BEFORE the poll (latency hides
// under the spin); the out-store is issued AFTER the flag release so its HBM
// writeback ack is off the critical release path.
// ---------------------------------------------------------------------------
__global__ __launch_bounds__(256) void lstm_scan(
    const float* __restrict__ Wh,      // [2048][512] fp32
    const float* __restrict__ gx,      // [T_C][32][2048] fp32
    float* __restrict__ out,           // [32][2048][512] ++ hfin[32][512] ++ cfin[32][512]
    ushort_t* __restrict__ hstate,     // [2][32][512] bf16 (parity buffers)
    float*    __restrict__ cstate,     // [32][512] fp32
    unsigned* __restrict__ flags,      // 32 flags, 128B apart: flags[w*32]
    int t0)
{
    const int w    = blockIdx.x;
    const int hb   = w * 16;
    const int tid  = threadIdx.x;
    const int lane = tid & 63;
    const int g    = tid >> 6;
    const int rsel = lane & 15;
    const int quad = lane >> 4;

    __shared__ float gs[4][32][16];    // [gate][batch][hidden]

    // persistent Wh fragments (bf16): B-operand, n = lane&15, k = quad*8 + kt*32 + j
    bf16x8 bfrag[16];
    {
        const float* wp = Wh + (size_t)(g * 512 + hb + rsel) * 512 + quad * 8;
#pragma unroll
        for (int kt = 0; kt < 16; kt++) bfrag[kt] = cvt8(wp + kt * 32);
    }

    const int eb = tid >> 3;           // batch 0..31
    const int eh = (tid & 7) * 2;      // hidden pair
    const size_t cidx = (size_t)eb * 512 + hb + eh;
    float c0 = 0.0f, c1 = 0.0f;
    if (t0 > 0) { c0 = cstate[cidx]; c1 = cstate[cidx + 1]; }
    float h0 = 0.0f, h1 = 0.0f;
    const size_t out_base = (size_t)eb * (T_SZ * H_SZ) + hb + eh;

    for (int tl = 0; tl < T_C; tl++) {
        const int t = t0 + tl;

        // ---- prefetch gx(t) into registers (independent of the flag wait) ----
        float gl0[4], gl1[4];
        {
            const float* gp = gx + (size_t)tl * (B_SZ * G_SZ) + (size_t)(g * 512 + hb + rsel);
#pragma unroll
            for (int r = 0; r < 4; r++) {
                const int b0 = quad * 4 + r;
                gl0[r] = gp[(size_t)b0 * G_SZ];
                gl1[r] = gp[(size_t)(b0 + 16) * G_SZ];
            }
        }
        __builtin_amdgcn_sched_barrier(0);   // keep the loads issued before the spin

        // ---- wait: all 32 WGs have published h(t) (per-wave, no extra sync) ----
        if (t > 0) {
            const unsigned tgt = (unsigned)t;
            for (;;) {
                unsigned f = __hip_atomic_load(&flags[(lane & 31) * 32],
                                               __ATOMIC_RELAXED, __HIP_MEMORY_SCOPE_AGENT);
                if (__all((int)(f >= tgt))) break;
            }
            __builtin_amdgcn_fence(__ATOMIC_ACQUIRE, "agent");
        }

        // ---- h(t) @ Wh^T : 4 independent MFMA chains for ILP ----
        f32x4 acc0a = (f32x4)0.0f, acc0b = (f32x4)0.0f;
        f32x4 acc1a = (f32x4)0.0f, acc1b = (f32x4)0.0f;
        if (t > 0) {
            const ushort_t* hp = hstate + (size_t)(t & 1) * (B_SZ * H_SZ)
                                 + (size_t)rsel * 512 + quad * 8;
#pragma unroll
            for (int kt = 0; kt < 16; kt += 2) {
                bf16x8 a0 = *(const bf16x8*)(hp + kt * 32);
                bf16x8 a1 = *(const bf16x8*)(hp + (size_t)16 * 512 + kt * 32);
                bf16x8 a2 = *(const bf16x8*)(hp + (kt + 1) * 32);
                bf16x8 a3 = *(const bf16x8*)(hp + (size_t)16 * 512 + (kt + 1) * 32);
                acc0a = __builtin_amdgcn_mfma_f32_16x16x32_bf16(a0, bfrag[kt],     acc0a, 0, 0, 0);
                acc1a = __builtin_amdgcn_mfma_f32_16x16x32_bf16(a1, bfrag[kt],     acc1a, 0, 0, 0);
                acc0b = __builtin_amdgcn_mfma_f32_16x16x32_bf16(a2, bfrag[kt + 1], acc0b, 0, 0, 0);
                acc1b = __builtin_amdgcn_mfma_f32_16x16x32_bf16(a3, bfrag[kt + 1], acc1b, 0, 0, 0);
            }
        }
        const f32x4 acc0 = acc0a + acc0b;
        const f32x4 acc1 = acc1a + acc1b;

        // C/D layout: col = lane&15 (hidden), row = quad*4 + r (batch)
#pragma unroll
        for (int r = 0; r < 4; r++) {
            const int b0 = quad * 4 + r;
            gs[g][b0][rsel]      = acc0[r] + gl0[r];
            gs[g][b0 + 16][rsel] = acc1[r] + gl1[r];
        }
        __syncthreads();

        // ---- elementwise gates + state update ----
        {
            const float ig0 = gs[0][eb][eh], ig1 = gs[0][eb][eh + 1];
            const float fg0 = gs[1][eb][eh], fg1 = gs[1][eb][eh + 1];
            const float cg0 = gs[2][eb][eh], cg1 = gs[2][eb][eh + 1];
            const float og0 = gs[3][eb][eh], og1 = gs[3][eb][eh + 1];
            c0 = sigf(fg0) * c0 + sigf(ig0) * tanh_fast(cg0);
            c1 = sigf(fg1) * c1 + sigf(ig1) * tanh_fast(cg1);
            h0 = sigf(og0) * tanh_fast(c0);
            h1 = sigf(og1) * tanh_fast(c1);
            // publish h(t+1) into parity buffer (t+1)&1
            const unsigned hpack = (unsigned)f2bf(h0) | ((unsigned)f2bf(h1) << 16);
            ushort_t* wrp = hstate + (size_t)((t + 1) & 1) * (B_SZ * H_SZ) + cidx;
            __hip_atomic_store((unsigned*)wrp, hpack, __ATOMIC_RELAXED, __HIP_MEMORY_SCOPE_AGENT);
        }
        __syncthreads();   // drains all lanes' h stores (vmcnt 0) + gs read/write fence

        if (tid == 0)
            __hip_atomic_store(&flags[w * 32], (unsigned)(t + 1),
                               __ATOMIC_RELEASE, __HIP_MEMORY_SCOPE_AGENT);

        // out store AFTER the release: its HBM ack drains at next step's sync,
        // off the critical publish path.
        f32x2 ho; ho[0] = h0; ho[1] = h1;
        *(f32x2*)(out + out_base + (size_t)t * H_SZ) = ho;
    }

    // persist c; finals at end of last chunk (fp32)
    cstate[cidx] = c0; cstate[cidx + 1] = c1;
    if (t0 + T_C == T_SZ) {
        float* hf = out + (size_t)B_SZ * T_SZ * H_SZ;
        f32x2 hv; hv[0] = h0; hv[1] = h1;
        *(f32x2*)(hf + cidx) = hv;
        float* cf = hf + B_SZ * H_SZ;
        f32x2 cv; cv[0] = c0; cv[1] = c1;
        *(f32x2*)(cf + cidx) = cv;
    }
}

extern "C" void kernel_launch(void* const* d_in, const int* in_sizes, int n_in,
                              void* d_out, int out_size, void* d_ws, size_t ws_size,
                              hipStream_t stream) {
    const float* x  = (const float*)d_in[0];
    const float* Wi = (const float*)d_in[1];
    const float* bi = (const float*)d_in[2];
    const float* Wh = (const float*)d_in[3];
    const float* bh = (const float*)d_in[4];
    float* out = (float*)d_out;

    const size_t GX_BYTES = (size_t)T_C * B_SZ * G_SZ * sizeof(float);      // 16 MiB
    float*    gxc    = (float*)d_ws;
    ushort_t* hstate = (ushort_t*)((char*)d_ws + GX_BYTES);                 // 64 KiB (2 parity)
    float*    cstate = (float*)   ((char*)d_ws + GX_BYTES + 65536);         // 64 KiB
    unsigned* flags  = (unsigned*)((char*)d_ws + GX_BYTES + 65536 + 65536); // 4 KiB

    hipMemsetAsync(flags, 0, 4096, stream);  // epoch flags: zero once per launch

    for (int k = 0; k < N_CHUNK; k++) {
        const int t0 = k * T_C;
        gemm_gx<<<dim3(G_SZ / 128, (B_SZ * T_C) / 128), dim3(256), 0, stream>>>(
            x, Wi, bi, bh, gxc, t0);
        lstm_scan<<<dim3(32), dim3(256), 0, stream>>>(Wh, gxc, out, hstate, cstate, flags, t0);
    }
}